// Round 8
// baseline (620.631 us; speedup 1.0000x reference)
//
#include <hip/hip_runtime.h>
#include <math.h>

#define TT 256
#define NI 29
#define HH 128
#define NC 29
#define ROWS 16

typedef _Float16 f16x8 __attribute__((ext_vector_type(8)));
typedef _Float16 f16x4 __attribute__((ext_vector_type(4)));
typedef float f32x4 __attribute__((ext_vector_type(4)));

// tanh(x) = 1 - 2/(e^{2x}+1); e^{2x} = 2^{2x*log2(e)}. Graceful at +-inf.
__device__ __forceinline__ float fast_tanh(float x) {
    float e = __builtin_amdgcn_exp2f(x * 2.885390081777927f);
    return 1.0f - 2.0f * __builtin_amdgcn_rcpf(e + 1.0f);
}

__device__ __forceinline__ f16x8 cvt8(const float4& a, const float4& b) {
    f16x8 r;
    r[0] = (_Float16)a.x; r[1] = (_Float16)a.y;
    r[2] = (_Float16)a.z; r[3] = (_Float16)a.w;
    r[4] = (_Float16)b.x; r[5] = (_Float16)b.y;
    r[6] = (_Float16)b.z; r[7] = (_Float16)b.w;
    return r;
}

__device__ __forceinline__ f16x4 tanh4(const f32x4& a) {
    f16x4 r;
#pragma unroll
    for (int q = 0; q < 4; ++q) r[q] = (_Float16)fast_tanh(a[q]);
    return r;
}

// per-lane chunk of x~ = [x(29), 1(bias col), 0, 0]: i = 8g..8g+7
__device__ __forceinline__ void load_xe(const float* p, int g, float4& a, float4& b) {
    a = *(const float4*)p;
    if (g < 3) {
        b = *(const float4*)(p + 4);
    } else {
        b.x = p[4];            // i = 28
        b.y = 1.0f;            // i = 29: constant-1 -> bias column
        b.z = 0.f; b.w = 0.f;
    }
}

#define MFMA16(A, B, C) __builtin_amdgcn_mfma_f32_16x16x32_f16((A), (B), (C), 0, 0, 0)

// Row permutation: accumulator a, C-row r hold Whh-output row J(a,r).
// Chosen so lane (m,g)'s C output {J(a,4g+q)} == its next-step B need
// {32s+8g+e}, making the recurrence register-local (no LDS/shuffles):
//   B-slice s = concat(acc[2s][0..3], acc[2s+1][0..3]) after tanh.
__device__ __forceinline__ int Jrow(int a, int r) {
    return 32 * (a >> 1) + 4 * (a & 1) + 8 * (r >> 2) + 2 * ((r >> 1) & 1) + (r & 1);
}

// W~ih[j][k]: k<29 -> Wih, k=29 -> bih+bhh (bias), else 0
__device__ __forceinline__ void load_rnn_W(
    const float* __restrict__ Wih, const float* __restrict__ Whh,
    const float* __restrict__ bih, const float* __restrict__ bhh,
    int m, int g, f16x8 (&Aw)[8][4], f16x8 (&AX)[8])
{
#pragma unroll
    for (int a = 0; a < 8; ++a) {
        const int j = Jrow(a, m);
#pragma unroll
        for (int s = 0; s < 4; ++s) {
            const float* p = Whh + j * HH + 32 * s + 8 * g;
            float4 v0 = *(const float4*)p;
            float4 v1 = *(const float4*)(p + 4);
            Aw[a][s] = cvt8(v0, v1);
        }
        f16x8 ax;
#pragma unroll
        for (int e = 0; e < 8; ++e) {
            int k = 8 * g + e;
            float v = (k < NI) ? Wih[j * NI + k]
                               : (k == NI ? bih[j] + bhh[j] : 0.f);
            ax[e] = (_Float16)v;
        }
        AX[a] = ax;
    }
}

// One step: Bh (registers) -> acc -> tanh -> Bh. MFMA 16x16x32 layouts
// (HW-verified via R2..R7 end-to-end passes):
//   A[r][k]: r = lane&15, k = (lane>>4)*8 + e
//   B[k][n]: n = lane&15, k = (lane>>4)*8 + e
//   C/D:     col = lane&15 (batch), row = (lane>>4)*4 + q
template <int DEC>
__device__ __forceinline__ void rstep(
    f16x8 (&Bh)[4], const f16x8 (&Aw)[8][4], const f16x8 (&AX)[8],
    const f16x8 (&Afc)[2][4], const float (&fcb0)[4], const float (&fcb1)[4],
    float4& xa, float4& xb, const float* xrow, int t, int g,
    float* outp)
{
    f16x8 BX = cvt8(xa, xb);
    if (t + 2 < TT) load_xe(xrow + (t + 2) * NI, g, xa, xb);

    const f32x4 zc = {0.f, 0.f, 0.f, 0.f};
    f32x4 ac[8];
#pragma unroll
    for (int a = 0; a < 8; ++a) ac[a] = MFMA16(AX[a], BX, zc);
#pragma unroll
    for (int s = 0; s < 4; ++s)
#pragma unroll
        for (int a = 0; a < 8; ++a) ac[a] = MFMA16(Aw[a][s], Bh[s], ac[a]);

#pragma unroll
    for (int s = 0; s < 4; ++s) {
        f16x4 lo = tanh4(ac[2 * s]);
        f16x4 hi = tanh4(ac[2 * s + 1]);
        f16x8 b;
        b[0] = lo[0]; b[1] = lo[1]; b[2] = lo[2]; b[3] = lo[3];
        b[4] = hi[0]; b[5] = hi[1]; b[6] = hi[2]; b[7] = hi[3];
        Bh[s] = b;
    }

    if (DEC) {
        f32x4 f0 = MFMA16(Afc[0][0], Bh[0], zc);
        f32x4 f1 = MFMA16(Afc[1][0], Bh[0], zc);
        f0 = MFMA16(Afc[0][1], Bh[1], f0);
        f1 = MFMA16(Afc[1][1], Bh[1], f1);
        f0 = MFMA16(Afc[0][2], Bh[2], f0);
        f1 = MFMA16(Afc[1][2], Bh[2], f1);
        f0 = MFMA16(Afc[0][3], Bh[3], f0);
        f1 = MFMA16(Afc[1][3], Bh[3], f1);
        float* op = outp + (long)t * NC;
#pragma unroll
        for (int q = 0; q < 4; ++q) {
            op[4 * g + q] = f0[q] + fcb0[q];          // c = 4g+q < 16
            int c = 16 + 4 * g + q;
            if (c < NC) op[c] = f1[q] + fcb1[q];
        }
    }
}

// One wave per block owns 16 batch rows end-to-end; h-state lives in
// registers for all 512 steps. No LDS, no barriers, no cross-lane ops.
__launch_bounds__(64, 1)
__global__ void seq2seq_fused(const float* __restrict__ enc_in,
                              const float* __restrict__ h0p,   // [1,B,H]
                              const float* __restrict__ dec_in,
                              const float* __restrict__ eWih,
                              const float* __restrict__ eWhh,
                              const float* __restrict__ ebih,
                              const float* __restrict__ ebhh,
                              const float* __restrict__ dWih,
                              const float* __restrict__ dWhh,
                              const float* __restrict__ dbih,
                              const float* __restrict__ dbhh,
                              const float* __restrict__ fcW,
                              const float* __restrict__ fcb,
                              float* __restrict__ out)
{
    const int lane = threadIdx.x & 63;
    const int m    = lane & 15;        // batch row within tile (C/B col)
    const int g    = lane >> 4;        // 0..3
    const int b0   = blockIdx.x * ROWS;

    f16x8 Aw[8][4], AX[8], Afc[2][4];
    float fcb0[4] = {}, fcb1[4] = {};
    f16x8 Bh[4];

    // h0 -> Bh: slice s = h0[batch m][32s+8g .. +7]
#pragma unroll
    for (int s = 0; s < 4; ++s) {
        const float* hp = h0p + (long)(b0 + m) * HH + 32 * s + 8 * g;
        float4 v0 = *(const float4*)hp;
        float4 v1 = *(const float4*)(hp + 4);
        Bh[s] = cvt8(v0, v1);
    }

    // ---------------- encoder ----------------
    load_rnn_W(eWih, eWhh, ebih, ebhh, m, g, Aw, AX);
    {
        const float* xrow = enc_in + ((long)(b0 + m) * TT) * NI + 8 * g;
        float4 xa0, xa1, xb0, xb1;
        load_xe(xrow + 0 * NI, g, xa0, xa1);
        load_xe(xrow + 1 * NI, g, xb0, xb1);
        for (int t = 0; t < TT; t += 2) {
            rstep<0>(Bh, Aw, AX, Afc, fcb0, fcb1, xa0, xa1, xrow, t,     g, nullptr);
            rstep<0>(Bh, Aw, AX, Afc, fcb0, fcb1, xb0, xb1, xrow, t + 1, g, nullptr);
        }
    }

    // ---------------- decoder (state hands off in registers) ----------------
    load_rnn_W(dWih, dWhh, dbih, dbhh, m, g, Aw, AX);
#pragma unroll
    for (int af = 0; af < 2; ++af) {
        const int c = 16 * af + m;
#pragma unroll
        for (int s = 0; s < 4; ++s) {
            f16x8 a;
#pragma unroll
            for (int e = 0; e < 8; ++e) {
                int k = 32 * s + 8 * g + e;
                a[e] = (c < NC) ? (_Float16)fcW[c * HH + k] : (_Float16)0.f;
            }
            Afc[af][s] = a;
        }
    }
#pragma unroll
    for (int q = 0; q < 4; ++q) {
        fcb0[q] = fcb[4 * g + q];
        int c = 16 + 4 * g + q;
        fcb1[q] = (c < NC) ? fcb[c] : 0.f;
    }
    {
        const float* xrow = dec_in + ((long)(b0 + m) * TT) * NI + 8 * g;
        float* outp = out + (long)(b0 + m) * TT * NC;
        float4 xa0, xa1, xb0, xb1;
        load_xe(xrow + 0 * NI, g, xa0, xa1);
        load_xe(xrow + 1 * NI, g, xb0, xb1);
        for (int t = 0; t < TT; t += 2) {
            rstep<1>(Bh, Aw, AX, Afc, fcb0, fcb1, xa0, xa1, xrow, t,     g, outp);
            rstep<1>(Bh, Aw, AX, Afc, fcb0, fcb1, xb0, xb1, xrow, t + 1, g, outp);
        }
    }
}

extern "C" void kernel_launch(void* const* d_in, const int* in_sizes, int n_in,
                              void* d_out, int out_size, void* d_ws, size_t ws_size,
                              hipStream_t stream) {
    const float* enc_in  = (const float*)d_in[0];
    const float* enc_h0  = (const float*)d_in[1];
    const float* dec_in  = (const float*)d_in[2];
    const float* enc_Wih = (const float*)d_in[3];
    const float* enc_Whh = (const float*)d_in[4];
    const float* enc_bih = (const float*)d_in[5];
    const float* enc_bhh = (const float*)d_in[6];
    const float* dec_Wih = (const float*)d_in[7];
    const float* dec_Whh = (const float*)d_in[8];
    const float* dec_bih = (const float*)d_in[9];
    const float* dec_bhh = (const float*)d_in[10];
    const float* fc_W    = (const float*)d_in[11];
    const float* fc_b    = (const float*)d_in[12];
    float* out = (float*)d_out;

    dim3 grid(2048 / ROWS), block(64);
    seq2seq_fused<<<grid, block, 0, stream>>>(enc_in, enc_h0, dec_in,
                                              enc_Wih, enc_Whh, enc_bih, enc_bhh,
                                              dec_Wih, dec_Whh, dec_bih, dec_bhh,
                                              fc_W, fc_b, out);
}

// Round 9
// 465.824 us; speedup vs baseline: 1.3323x; 1.3323x over previous
//
#include <hip/hip_runtime.h>
#include <math.h>

#define TT 256
#define NI 29
#define HH 128
#define NC 29
#define ROWS 16
#define PSTR 136   // fp16 plane stride (halfs); 272 B rows -> 4-bank row shift

typedef _Float16 f16x8 __attribute__((ext_vector_type(8)));
typedef _Float16 f16x4 __attribute__((ext_vector_type(4)));
typedef float f32x4 __attribute__((ext_vector_type(4)));

// tanh(x) = 1 - 2/(e^{2x}+1); e^{2x} = 2^{2x*log2(e)}. Graceful at +-inf.
__device__ __forceinline__ float fast_tanh(float x) {
    float e = __builtin_amdgcn_exp2f(x * 2.885390081777927f);
    return 1.0f - 2.0f * __builtin_amdgcn_rcpf(e + 1.0f);
}

__device__ __forceinline__ f16x8 cvt8(const float4& a, const float4& b) {
    f16x8 r;
    r[0] = (_Float16)a.x; r[1] = (_Float16)a.y;
    r[2] = (_Float16)a.z; r[3] = (_Float16)a.w;
    r[4] = (_Float16)b.x; r[5] = (_Float16)b.y;
    r[6] = (_Float16)b.z; r[7] = (_Float16)b.w;
    return r;
}

__device__ __forceinline__ f16x4 tanh4(const f32x4& a) {
    f16x4 r;
#pragma unroll
    for (int q = 0; q < 4; ++q) r[q] = (_Float16)fast_tanh(a[q]);
    return r;
}

__device__ __forceinline__ f16x8 pack44(const f16x4& a, const f16x4& b) {
    f16x8 r;
    r[0] = a[0]; r[1] = a[1]; r[2] = a[2]; r[3] = a[3];
    r[4] = b[0]; r[5] = b[1]; r[6] = b[2]; r[7] = b[3];
    return r;
}

// per-lane chunk of x~ = [x(29), 1(bias col), 0, 0]: i = 8g..8g+7
__device__ __forceinline__ void load_xe(const float* p, int g, float4& a, float4& b) {
    a = *(const float4*)p;
    if (g < 3) {
        b = *(const float4*)(p + 4);
    } else {
        b.x = p[4];            // i = 28
        b.y = 1.0f;            // i = 29: constant-1 -> bias column
        b.z = 0.f; b.w = 0.f;
    }
}

#define MFMA16(A, B, C) __builtin_amdgcn_mfma_f32_16x16x32_f16((A), (B), (C), 0, 0, 0)

// J-permutation (R8-verified pattern, per-wave form): acc a, C-row r hold
// Whh row J(a,r) = 32w + 4a + 8*(r>>2) + (r&3). Then lane (m,g)'s packed
// output [acc0.q0..3, acc1.q0..3] == h[32w+8g+e], e=0..7 — exactly its own
// B-slice s=w: the own quarter of h never leaves registers.
// A-fragments in CONSUMPTION order k: slice s=(w+k)&3 (static reg indexing).
__device__ __forceinline__ void load_rnn_W(
    const float* __restrict__ Wih, const float* __restrict__ Whh,
    const float* __restrict__ bih, const float* __restrict__ bhh,
    int w, int m, int g, f16x8 (&AwO)[2][4], f16x8 (&AXO)[2])
{
#pragma unroll
    for (int a = 0; a < 2; ++a) {
        const int j = 32 * w + 4 * a + 8 * (m >> 2) + (m & 3);
#pragma unroll
        for (int k = 0; k < 4; ++k) {
            const int s = (w + k) & 3;
            const float* p = Whh + j * HH + 32 * s + 8 * g;
            AwO[a][k] = cvt8(*(const float4*)p, *(const float4*)(p + 4));
        }
        f16x8 ax;
#pragma unroll
        for (int e = 0; e < 8; ++e) {
            int kk = 8 * g + e;
            float v = (kk < NI) ? Wih[j * NI + kk]
                                : (kk == NI ? bih[j] + bhh[j] : 0.f);
            ax[e] = (_Float16)v;
        }
        AXO[a] = ax;
    }
}

// One step. Pre-barrier chain: MFMAs -> tanh -> own-slice ds_write -> lgkm0 ->
// s_barrier. Post-barrier shadow: issue next step's 3 ds_reads, then FC MFMAs
// (on register copies of h_t), stores, x prefetch — all overlap read latency.
#define STEP(CUR, XA, XB, TV, DECF)                                           \
  {                                                                           \
    f16x8 BX = cvt8(XA, XB);                                                  \
    f16x8 cb0 = own, cb1 = rd0, cb2 = rd1, cb3 = rd2;                         \
    f32x4 p00 = MFMA16(AXO[0], BX, zc);                                       \
    f32x4 p10 = MFMA16(AXO[1], BX, zc);                                       \
    p00 = MFMA16(AwO[0][0], cb0, p00);                                        \
    p10 = MFMA16(AwO[1][0], cb0, p10);                                        \
    f32x4 p01 = MFMA16(AwO[0][1], cb1, zc);                                   \
    f32x4 p11 = MFMA16(AwO[1][1], cb1, zc);                                   \
    p00 = MFMA16(AwO[0][2], cb2, p00);                                        \
    p10 = MFMA16(AwO[1][2], cb2, p10);                                        \
    p01 = MFMA16(AwO[0][3], cb3, p01);                                        \
    p11 = MFMA16(AwO[1][3], cb3, p11);                                        \
    if ((TV) + 2 < TT) load_xe(xrow + ((TV) + 2) * NI, g, XA, XB);            \
    f32x4 ac0 = p00 + p01, ac1 = p10 + p11;                                   \
    f16x4 t0 = tanh4(ac0), t1 = tanh4(ac1);                                   \
    own = pack44(t0, t1);                                                     \
    *(f16x8*)&planes[(CUR) ^ 1][m][wr_off] = own;                             \
    asm volatile("s_waitcnt lgkmcnt(0)" ::: "memory");                        \
    __builtin_amdgcn_s_barrier();                                             \
    __builtin_amdgcn_sched_barrier(0);                                        \
    rd0 = *(const f16x8*)&planes[(CUR) ^ 1][m][rb1];                          \
    rd1 = *(const f16x8*)&planes[(CUR) ^ 1][m][rb2];                          \
    rd2 = *(const f16x8*)&planes[(CUR) ^ 1][m][rb3];                          \
    if ((DECF) && w >= 2 && (TV) > 0) {                                       \
      f32x4 f0 = MFMA16(AfcO[0], cb0, zc);                                    \
      f0 = MFMA16(AfcO[1], cb1, f0);                                          \
      f0 = MFMA16(AfcO[2], cb2, f0);                                          \
      f0 = MFMA16(AfcO[3], cb3, f0);                                          \
      float* op = outp + (long)((TV) - 1) * NC + cbase;                       \
      _Pragma("unroll") for (int q = 0; q < 4; ++q)                           \
        if (cbase + q < NC) op[q] = f0[q] + fcbv[q];                          \
    }                                                                         \
  }

// 128 blocks x 256 threads (4 waves on the CU's 4 SIMDs). Wave w owns
// j in [32w, 32w+32): 10 MFMAs/step spread across 4 matrix pipes. Own h
// quarter stays in registers (J-permutation); other 3 quarters via one
// b128 write + three b128 reads per step (reads latency-hoisted).
__launch_bounds__(256, 1)
__global__ void seq2seq_fused(const float* __restrict__ enc_in,
                              const float* __restrict__ h0p,   // [1,B,H]
                              const float* __restrict__ dec_in,
                              const float* __restrict__ eWih,
                              const float* __restrict__ eWhh,
                              const float* __restrict__ ebih,
                              const float* __restrict__ ebhh,
                              const float* __restrict__ dWih,
                              const float* __restrict__ dWhh,
                              const float* __restrict__ dbih,
                              const float* __restrict__ dbhh,
                              const float* __restrict__ fcW,
                              const float* __restrict__ fcb,
                              float* __restrict__ out)
{
    __shared__ __align__(16) _Float16 planes[2][ROWS][PSTR];

    const int tid  = threadIdx.x;
    const int w    = tid >> 6;          // wave 0..3
    const int lane = tid & 63;
    const int m    = lane & 15;         // batch row (B/C col; A row role)
    const int g    = lane >> 4;         // 0..3
    const int b0   = blockIdx.x * ROWS;

    const int wr_off = 32 * w + 8 * g;                 // own slice (halfs)
    const int rb1 = 32 * ((w + 1) & 3) + 8 * g;        // others, consumption order
    const int rb2 = 32 * ((w + 2) & 3) + 8 * g;
    const int rb3 = 32 * ((w + 3) & 3) + 8 * g;

    const f32x4 zc = {0.f, 0.f, 0.f, 0.f};

    f16x8 AwO[2][4], AXO[2], AfcO[4];
    float fcbv[4] = {};
    f16x8 own, rd0, rd1, rd2;

    // ---- encoder weights ----
    load_rnn_W(eWih, eWhh, ebih, ebhh, w, m, g, AwO, AXO);

    // ---- h0: own slice to regs + LDS; prologue reads after sync ----
    {
        const float* hp = h0p + (long)(b0 + m) * HH + wr_off;
        own = cvt8(*(const float4*)hp, *(const float4*)(hp + 4));
        *(f16x8*)&planes[0][m][wr_off] = own;
    }
    __syncthreads();
    rd0 = *(const f16x8*)&planes[0][m][rb1];
    rd1 = *(const f16x8*)&planes[0][m][rb2];
    rd2 = *(const f16x8*)&planes[0][m][rb3];

    const float* xrow = enc_in + (long)(b0 + m) * TT * NI + 8 * g;
    float* outp = out + (long)(b0 + m) * TT * NC;
    int cbase = 0;                        // set for FC waves below

    float4 xa0, xa1, xb0, xb1;
    load_xe(xrow, g, xa0, xa1);
    load_xe(xrow + NI, g, xb0, xb1);

    for (int t = 0; t < TT; t += 2) {
        STEP(0, xa0, xa1, t, 0);
        STEP(1, xb0, xb1, t + 1, 0);
    }

    // ---- decoder: state hands off via regs (own) + planes[0] (rd issued) ----
    load_rnn_W(dWih, dWhh, dbih, dbhh, w, m, g, AwO, AXO);
    if (w >= 2) {
        const int ct = w - 2;             // c-tile 0 or 1
        cbase = 16 * ct + 4 * g;
        const int c = 16 * ct + m;
#pragma unroll
        for (int k = 0; k < 4; ++k) {
            const int s = (w + k) & 3;
            f16x8 a;
#pragma unroll
            for (int e = 0; e < 8; ++e) {
                int kk = 32 * s + 8 * g + e;
                a[e] = (c < NC) ? (_Float16)fcW[c * HH + kk] : (_Float16)0.f;
            }
            AfcO[k] = a;
        }
#pragma unroll
        for (int q = 0; q < 4; ++q) {
            int c2 = cbase + q;
            fcbv[q] = (c2 < NC) ? fcb[c2] : 0.f;
        }
    }
    xrow = dec_in + (long)(b0 + m) * TT * NI + 8 * g;
    load_xe(xrow, g, xa0, xa1);
    load_xe(xrow + NI, g, xb0, xb1);

    for (int t = 0; t < TT; t += 2) {
        STEP(0, xa0, xa1, t, 1);
        STEP(1, xb0, xb1, t + 1, 1);
    }

    // ---- epilogue FC: out[TT-1] on the final state (own + rd just issued) ----
    if (w >= 2) {
        f32x4 f0 = MFMA16(AfcO[0], own, zc);
        f0 = MFMA16(AfcO[1], rd0, f0);
        f0 = MFMA16(AfcO[2], rd1, f0);
        f0 = MFMA16(AfcO[3], rd2, f0);
        float* op = outp + (long)(TT - 1) * NC + cbase;
#pragma unroll
        for (int q = 0; q < 4; ++q)
            if (cbase + q < NC) op[q] = f0[q] + fcbv[q];
    }
}

extern "C" void kernel_launch(void* const* d_in, const int* in_sizes, int n_in,
                              void* d_out, int out_size, void* d_ws, size_t ws_size,
                              hipStream_t stream) {
    const float* enc_in  = (const float*)d_in[0];
    const float* enc_h0  = (const float*)d_in[1];
    const float* dec_in  = (const float*)d_in[2];
    const float* enc_Wih = (const float*)d_in[3];
    const float* enc_Whh = (const float*)d_in[4];
    const float* enc_bih = (const float*)d_in[5];
    const float* enc_bhh = (const float*)d_in[6];
    const float* dec_Wih = (const float*)d_in[7];
    const float* dec_Whh = (const float*)d_in[8];
    const float* dec_bih = (const float*)d_in[9];
    const float* dec_bhh = (const float*)d_in[10];
    const float* fc_W    = (const float*)d_in[11];
    const float* fc_b    = (const float*)d_in[12];
    float* out = (float*)d_out;

    dim3 grid(2048 / ROWS), block(256);
    seq2seq_fused<<<grid, block, 0, stream>>>(enc_in, enc_h0, dec_in,
                                              enc_Wih, enc_Whh, enc_bih, enc_bhh,
                                              dec_Wih, dec_Whh, dec_bih, dec_bhh,
                                              fc_W, fc_b, out);
}